// Round 13
// baseline (83.983 us; speedup 1.0000x reference)
//
#include <hip/hip_runtime.h>
#include <hip/hip_bf16.h>

typedef __attribute__((ext_vector_type(4))) float f32x4;
typedef __attribute__((ext_vector_type(8))) short bf16x8;
typedef __attribute__((ext_vector_type(4))) unsigned int u32x4;

#define M_TOT 30752   // 8*62*62 output pixels

__device__ __forceinline__ unsigned short f2bf(float f) {
  unsigned int u = __float_as_uint(f);
  u = u + 0x7FFF + ((u >> 16) & 1);   // round-to-nearest-even
  return (unsigned short)(u >> 16);
}

__device__ __forceinline__ void gload16(const void* g, void* l) {
  __builtin_amdgcn_global_load_lds((const __attribute__((address_space(1))) unsigned int*)g,
                                   (__attribute__((address_space(3))) unsigned int*)l,
                                   16, 0, 0);
}

// D.lo16 = bf16(lo), D.hi16 = bf16(hi)
#define CVT_PK(dst, lo, hi) \
  asm("v_cvt_pk_bf16_f32 %0, %1, %2" : "=v"(dst) : "v"(lo), "v"(hi))

// ---- keff: block = o (256 blocks), thread = f. S slice read once (16 rows),
// all 9 taps from registers.
__global__ __launch_bounds__(256) void keff_k(const float* __restrict__ Q,
                                              const float* __restrict__ S,
                                              float* __restrict__ Keff) {
  const int o = blockIdx.x;          // 0..255
  const int t = threadIdx.x;
  float s[16];
  const float* sp = S + (o >> 4) * 4096 + (o & 15) * 256 + t;   // coalesced across f
#pragma unroll
  for (int bi = 0; bi < 16; ++bi) s[bi] = sp[bi * 65536];
  const float* qp = Q + o * 144;                                 // uniform -> s_load
#pragma unroll
  for (int kk = 0; kk < 9; ++kk) {
    float a = 0.f;
#pragma unroll
    for (int bi = 0; bi < 16; ++bi) a = fmaf(qp[kk * 16 + bi], s[bi], a);
    Keff[(o * 9 + kk) * 256 + t] = a;
  }
}

// ---- k2t: K2t[kk][f][ci] = sum_o P[o][ci] * Keff[o][kk][f]  (bf16, transposed)
__global__ __launch_bounds__(256) void k2t_k(const float* __restrict__ P,
                                             const float* __restrict__ Keff,
                                             unsigned short* __restrict__ K2t) {
  const int kk = blockIdx.x >> 6;        // 0..8
  const int f0 = (blockIdx.x & 63) * 4;  // 0..252
  const int ci = threadIdx.x;
  float acc[4] = {0.f, 0.f, 0.f, 0.f};
#pragma unroll 8
  for (int o = 0; o < 256; ++o) {
    float pv = P[o * 256 + ci];                        // coalesced
    const float* ke = Keff + (o * 9 + kk) * 256 + f0;  // uniform -> s_load_dwordx4
    acc[0] = fmaf(pv, ke[0], acc[0]);
    acc[1] = fmaf(pv, ke[1], acc[1]);
    acc[2] = fmaf(pv, ke[2], acc[2]);
    acc[3] = fmaf(pv, ke[3], acc[3]);
  }
#pragma unroll
  for (int j = 0; j < 4; ++j)
    K2t[kk * 65536 + (f0 + j) * 256 + ci] = f2bf(acc[j]);
}

// ---- main: implicit-GEMM conv, A staged DIRECTLY from f32 x (cast fused).
// M=30752, N=256, K=2304. BM=128, BN=128, BK=64/step; 4 waves (sk x wn),
// wave tile 128m x 64n over its K-half. A: reg-stage 8 dwordx4 (f32) issued
// early -> compute -> vmcnt(4) -> cvt_pk x16 -> ds_write_b128 x4 (T14 split).
// B: global_load_lds. Mixed vmcnt ledger: top vmcnt(12) retires B(t);
// post-compute vmcnt(4) retires A(t+1). One barrier/step. Conflict-free
// 64B-row swizzle (R10, measured 0). 2 blocks/CU; grid 488 = 8 XCD x 61.
__global__ __launch_bounds__(256, 2) void conv_gemm(const float* __restrict__ x,
                                                    const unsigned short* __restrict__ K2t,
                                                    float* __restrict__ out) {
  __shared__ __attribute__((aligned(16))) char smem[65536];  // 2 x (A16K + B16K)

  const int tid = threadIdx.x;
  const int lane = tid & 63;
  const int wid = tid >> 6;         // 0..3
  const int sk = wid >> 1;          // k-half
  const int wn = wid & 1;           // n-half

  const int wgid = (blockIdx.x & 7) * 61 + (blockIdx.x >> 3);
  if (wgid >= 482) return;
  const int mt = wgid >> 1;         // 0..240
  const int nt = wgid & 1;
  const int m0 = mt * 128;
  const int n0 = nt * 128;

  const int rl = lane & 15;
  const int kg = lane >> 4;

  // chunk (stored slot sl, row r) holds data-slot d = sl ^ ((r>>1)&3).
  // thread t owns chunks {t, t+256, t+512, t+768}: (row t>>2, sk0), (row+64,
  // sk0), (row, sk1), (row+64, sk1); source slot s_src = (t&3)^((t>>3)&3).
  const int s_src = ((tid & 3) ^ ((tid >> 3) & 3)) * 8;   // element offset
  int gA0, gA1;
  {
    int m = m0 + (tid >> 2); if (m >= M_TOT) m = M_TOT - 1;
    int b = m / 3844; int rem = m - b * 3844;
    int h = rem / 62; int w = rem - h * 62;
    gA0 = ((b * 64 + h) * 64 + w) * 256 + s_src;          // f32 element index
    m = m0 + (tid >> 2) + 64; if (m >= M_TOT) m = M_TOT - 1;
    b = m / 3844; rem = m - b * 3844;
    h = rem / 62; w = rem - h * 62;
    gA1 = ((b * 64 + h) * 64 + w) * 256 + s_src;
  }
  const int fB0 = (n0 + (tid >> 2)) * 256 + s_src;        // B rows f, f+64
  const int fB1 = (n0 + (tid >> 2) + 64) * 256 + s_src;

  f32x4 zero = {0.f, 0.f, 0.f, 0.f};
  f32x4 acc[8][4];
#pragma unroll
  for (int i = 0; i < 8; ++i)
#pragma unroll
    for (int j = 0; j < 4; ++j) acc[i][j] = zero;

  f32x4 av[8];                      // in-flight A tile (f32), statically indexed

  // read-side: stored slot = kg ^ ((rl>>1)&3)
  const int slotr = (kg ^ ((rl >> 1) & 3)) * 16;              // bytes
  const int aoff = sk * 8192 + rl * 64 + slotr;               // A region bytes
  const int boff = 16384 + sk * 8192 + (wn * 64 + rl) * 64 + slotr;  // B region

#define A_LOAD(t)                                                              \
  {                                                                            \
    int kk_ = (t) >> 2, cb_ = (t) & 3;                                         \
    int kh_ = kk_ / 3, kw_ = kk_ - kh_ * 3;                                    \
    int offA_ = kh_ * 16384 + kw_ * 256 + cb_ * 64;                            \
    const f32x4* p0 = (const f32x4*)(x + gA0 + offA_);                         \
    const f32x4* p1 = (const f32x4*)(x + gA1 + offA_);                         \
    av[0] = p0[0]; av[1] = p0[1];                                              \
    av[2] = p1[0]; av[3] = p1[1];                                              \
    av[4] = p0[8]; av[5] = p0[9];  /* +32 floats (sk1) */                      \
    av[6] = p1[8]; av[7] = p1[9];                                              \
  }

#define STAGE_B(t, base)                                                       \
  {                                                                            \
    int kk_ = (t) >> 2, cb_ = (t) & 3;                                         \
    int offB_ = kk_ * 65536 + cb_ * 64;                                        \
    unsigned short* bB = (unsigned short*)((char*)(base) + 16384);             \
    gload16(K2t + offB_ + fB0,      bB + tid * 8);                             \
    gload16(K2t + offB_ + fB1,      bB + (tid + 256) * 8);                     \
    gload16(K2t + offB_ + fB0 + 32, bB + (tid + 512) * 8);                     \
    gload16(K2t + offB_ + fB1 + 32, bB + (tid + 768) * 8);                     \
  }

#define A_WRITE(base)                                                          \
  {                                                                            \
    unsigned short* bA = (unsigned short*)(base);                              \
    _Pragma("unroll")                                                          \
    for (int q = 0; q < 4; ++q) {                                              \
      unsigned int w0, w1, w2, w3;                                             \
      CVT_PK(w0, av[2 * q][0], av[2 * q][1]);                                  \
      CVT_PK(w1, av[2 * q][2], av[2 * q][3]);                                  \
      CVT_PK(w2, av[2 * q + 1][0], av[2 * q + 1][1]);                          \
      CVT_PK(w3, av[2 * q + 1][2], av[2 * q + 1][3]);                          \
      u32x4 w = {w0, w1, w2, w3};                                              \
      *(u32x4*)(bA + (tid + 256 * q) * 8) = w;   /* ds_write_b128 */           \
    }                                                                          \
  }

  // prologue: fill buffer 0
  A_LOAD(0);
  __builtin_amdgcn_sched_barrier(0);
  STAGE_B(0, smem);
  asm volatile("s_waitcnt vmcnt(4)" ::: "memory");   // A(0) regs done
  __builtin_amdgcn_sched_barrier(0);
  A_WRITE(smem);                                      // B(0) still in flight (4)

  for (int t = 0; t < 36; ++t) {
    char* cur = smem + (t & 1) * 32768;
    char* nxt = smem + ((t + 1) & 1) * 32768;

    if (t < 35) {
      A_LOAD(t + 1);                                  // 8 vmem -> regs
      __builtin_amdgcn_sched_barrier(0);
      STAGE_B(t + 1, nxt);                            // 4 gload_lds
      asm volatile("s_waitcnt vmcnt(12)" ::: "memory");  // B(t) landed
    } else {
      asm volatile("s_waitcnt vmcnt(0)" ::: "memory");
    }
    asm volatile("s_waitcnt lgkmcnt(0)" ::: "memory");   // A(t) ds_writes drained
    __builtin_amdgcn_sched_barrier(0);
    __builtin_amdgcn_s_barrier();                        // tile t visible to all
    __builtin_amdgcn_sched_barrier(0);

    // compute tile t: bfr first, af staggered 2-at-a-time (R11 order)
    bf16x8 bfr[4];
#pragma unroll
    for (int ni = 0; ni < 4; ++ni)
      bfr[ni] = *(const bf16x8*)(cur + boff + ni * 1024);
    bf16x8 a0 = *(const bf16x8*)(cur + aoff);
    bf16x8 a1 = *(const bf16x8*)(cur + aoff + 1024);
#pragma unroll
    for (int j = 0; j < 4; ++j) {
      bf16x8 a2, a3;
      if (j < 3) {
        a2 = *(const bf16x8*)(cur + aoff + (2 * j + 2) * 1024);
        a3 = *(const bf16x8*)(cur + aoff + (2 * j + 3) * 1024);
      }
      __builtin_amdgcn_s_setprio(1);
#pragma unroll
      for (int ni = 0; ni < 4; ++ni)
        acc[2 * j][ni] = __builtin_amdgcn_mfma_f32_16x16x32_bf16(
            a0, bfr[ni], acc[2 * j][ni], 0, 0, 0);
#pragma unroll
      for (int ni = 0; ni < 4; ++ni)
        acc[2 * j + 1][ni] = __builtin_amdgcn_mfma_f32_16x16x32_bf16(
            a1, bfr[ni], acc[2 * j + 1][ni], 0, 0, 0);
      __builtin_amdgcn_s_setprio(0);
      a0 = a2; a1 = a3;
    }

    if (t < 35) {
      asm volatile("s_waitcnt vmcnt(4)" ::: "memory");   // A(t+1) regs arrived
      __builtin_amdgcn_sched_barrier(0);
      A_WRITE(nxt);                                       // cvt + ds_write
    }
  }

  // epilogue: sk=1 waves stage acc in LDS (64KB exactly); sk=0 adds + stores.
  // D row = kg*4 + r (+16*mi), col = rl (+16*ni +64*wn).
  float* red = (float*)smem;
  __syncthreads();
  if (sk == 1) {
#pragma unroll
    for (int mi = 0; mi < 8; ++mi)
#pragma unroll
      for (int ni = 0; ni < 4; ++ni)
        *(f32x4*)((char*)red + (((wn * 8 + mi) * 4 + ni) * 64 + lane) * 16) =
            acc[mi][ni];
  }
  __syncthreads();
  if (sk == 0) {
#pragma unroll
    for (int mi = 0; mi < 8; ++mi) {
      int mb = m0 + mi * 16 + kg * 4;
#pragma unroll
      for (int ni = 0; ni < 4; ++ni) {
        f32x4 o = *(f32x4*)((char*)red + (((wn * 8 + mi) * 4 + ni) * 64 + lane) * 16);
        o += acc[mi][ni];
        int f = n0 + wn * 64 + ni * 16 + rl;
#pragma unroll
        for (int r = 0; r < 4; ++r) {
          int m = mb + r;
          if (m < M_TOT) out[m * 256 + f] = o[r];
        }
      }
    }
  }
#undef A_LOAD
#undef STAGE_B
#undef A_WRITE
}

extern "C" void kernel_launch(void* const* d_in, const int* in_sizes, int n_in,
                              void* d_out, int out_size, void* d_ws, size_t ws_size,
                              hipStream_t stream) {
  const float* x = (const float*)d_in[0];   // [8,64,64,256]
  const float* P = (const float*)d_in[1];   // [256,256]
  const float* Q = (const float*)d_in[2];   // [256,3,3,16]
  const float* S = (const float*)d_in[3];   // [256,16,256]
  float* out = (float*)d_out;               // [8,62,62,256]

  char* ws = (char*)d_ws;
  unsigned short* K2t  = (unsigned short*)ws;              // 1,179,648 B
  float*          Keff = (float*)(ws + 1179648);           // 2,359,296 B

  keff_k<<<256, 256, 0, stream>>>(Q, S, Keff);
  k2t_k<<<576, 256, 0, stream>>>(P, Keff, K2t);
  conv_gemm<<<488, 256, 0, stream>>>(x, K2t, out);
}

// Round 14
// 74.772 us; speedup vs baseline: 1.1232x; 1.1232x over previous
//
#include <hip/hip_runtime.h>
#include <hip/hip_bf16.h>

typedef __attribute__((ext_vector_type(4))) float f32x4;
typedef __attribute__((ext_vector_type(8))) short bf16x8;

#define M_TOT 30752   // 8*62*62 output pixels

__device__ __forceinline__ unsigned short f2bf(float f) {
  unsigned int u = __float_as_uint(f);
  u = u + 0x7FFF + ((u >> 16) & 1);   // round-to-nearest-even
  return (unsigned short)(u >> 16);
}

__device__ __forceinline__ void gload16(const void* g, void* l) {
  __builtin_amdgcn_global_load_lds((const __attribute__((address_space(1))) unsigned int*)g,
                                   (__attribute__((address_space(3))) unsigned int*)l,
                                   16, 0, 0);
}

// ---- keff: block = o (256 blocks), thread = f. S slice read once (16 rows),
// all 9 taps from registers. Runs first (k2t depends on it; cast does not).
__global__ __launch_bounds__(256) void keff_k(const float* __restrict__ Q,
                                              const float* __restrict__ S,
                                              float* __restrict__ Keff) {
  const int o = blockIdx.x;          // 0..255
  const int t = threadIdx.x;
  float s[16];
  const float* sp = S + (o >> 4) * 4096 + (o & 15) * 256 + t;   // coalesced across f
#pragma unroll
  for (int bi = 0; bi < 16; ++bi) s[bi] = sp[bi * 65536];
  const float* qp = Q + o * 144;                                 // uniform -> s_load
#pragma unroll
  for (int kk = 0; kk < 9; ++kk) {
    float a = 0.f;
#pragma unroll
    for (int bi = 0; bi < 16; ++bi) a = fmaf(qp[kk * 16 + bi], s[bi], a);
    Keff[(o * 9 + kk) * 256 + t] = a;
  }
}

// ---- fused: blocks 0..575 = k2t (latency-bound, hides under cast);
//             blocks 576..4671 = cast x -> bf16 (HBM-bound, fills machine).
__global__ __launch_bounds__(256) void fused_k(const float* __restrict__ x,
                                               const float* __restrict__ P,
                                               const float* __restrict__ Keff,
                                               unsigned short* __restrict__ xb,
                                               unsigned short* __restrict__ K2t) {
  const int bid = blockIdx.x;
  const int t = threadIdx.x;

  if (bid >= 576) {                  // ---- cast x -> bf16 ----
    int i = (bid - 576) * 256 + t;
    const f32x4* xp = (const f32x4*)x;
    f32x4 a = xp[2 * i];
    f32x4 b = xp[2 * i + 1];
    bf16x8 o;
    o[0] = (short)f2bf(a[0]); o[1] = (short)f2bf(a[1]);
    o[2] = (short)f2bf(a[2]); o[3] = (short)f2bf(a[3]);
    o[4] = (short)f2bf(b[0]); o[5] = (short)f2bf(b[1]);
    o[6] = (short)f2bf(b[2]); o[7] = (short)f2bf(b[3]);
    ((bf16x8*)xb)[i] = o;
    return;
  }

  // ---- k2t: K2t[kk][f][ci] = sum_o P[o][ci] * Keff[o][kk][f] (bf16, transposed)
  const int kk = bid / 64;           // 0..8
  const int f0 = (bid & 63) * 4;     // 0..252
  const int ci = t;
  float acc[4] = {0.f, 0.f, 0.f, 0.f};
#pragma unroll 8
  for (int o = 0; o < 256; ++o) {
    float pv = P[o * 256 + ci];                        // coalesced
    const float* ke = Keff + (o * 9 + kk) * 256 + f0;  // uniform -> s_load_dwordx4
    acc[0] = fmaf(pv, ke[0], acc[0]);
    acc[1] = fmaf(pv, ke[1], acc[1]);
    acc[2] = fmaf(pv, ke[2], acc[2]);
    acc[3] = fmaf(pv, ke[3], acc[3]);
  }
#pragma unroll
  for (int j = 0; j < 4; ++j)
    K2t[kk * 65536 + (f0 + j) * 256 + ci] = f2bf(acc[j]);
}

// ---- main: implicit-GEMM conv.  M=30752, N=256, K=2304.  [R12, frozen]
// BM=128, BN=128, BK=64/step; 256 thr = 4 waves (sk x wn in 2x2), wave tile
// 128m x 64n over its K-half. Double-buffer 64KB LDS -> 2 blocks/CU.
// Counted vmcnt(8), 2 raw barriers/step. Conflict-free 64B-row swizzle
// (measured 0 conflicts). Grid 488 = 8 XCD x 61: (nt=0,1) pair shares A-tile.
__global__ __launch_bounds__(256, 2) void conv_gemm(const unsigned short* __restrict__ xb,
                                                    const unsigned short* __restrict__ K2t,
                                                    float* __restrict__ out) {
  __shared__ __attribute__((aligned(16))) char smem[65536];  // 2 x (A16K + B16K)

  const int tid = threadIdx.x;
  const int lane = tid & 63;
  const int wid = tid >> 6;         // 0..3
  const int sk = wid >> 1;          // k-half
  const int wn = wid & 1;           // n-half

  const int wgid = (blockIdx.x & 7) * 61 + (blockIdx.x >> 3);
  if (wgid >= 482) return;
  const int mt = wgid >> 1;         // 0..240
  const int nt = wgid & 1;
  const int m0 = mt * 128;
  const int n0 = nt * 128;

  const int rl = lane & 15;
  const int kg = lane >> 4;

  // staging: thread t owns chunks {t, t+256, t+512, t+768}; source slot
  // pre-swizzled s_src = (t&3) ^ ((t>>3)&3)  [row = t>>2]
  const int s_src = ((tid & 3) ^ ((tid >> 3) & 3)) * 8;   // element offset
  int gA0, gA1;
  {
    int m = m0 + (tid >> 2); if (m >= M_TOT) m = M_TOT - 1;
    int b = m / 3844; int rem = m - b * 3844;
    int h = rem / 62; int w = rem - h * 62;
    gA0 = ((b * 64 + h) * 64 + w) * 256 + s_src;
    m = m0 + (tid >> 2) + 64; if (m >= M_TOT) m = M_TOT - 1;
    b = m / 3844; rem = m - b * 3844;
    h = rem / 62; w = rem - h * 62;
    gA1 = ((b * 64 + h) * 64 + w) * 256 + s_src;
  }
  const int fB0 = (n0 + (tid >> 2)) * 256 + s_src;        // B rows f, f+64
  const int fB1 = (n0 + (tid >> 2) + 64) * 256 + s_src;

  f32x4 zero = {0.f, 0.f, 0.f, 0.f};
  f32x4 acc[8][4];
#pragma unroll
  for (int i = 0; i < 8; ++i)
#pragma unroll
    for (int j = 0; j < 4; ++j) acc[i][j] = zero;

  // read-side: slot = kg ^ ((rl>>1)&3); mi/ni stride 16 rows = 1024B
  const int slotr = (kg ^ ((rl >> 1) & 3)) * 16;              // bytes
  const int aoff = sk * 8192 + rl * 64 + slotr;               // A region bytes
  const int boff = 16384 + sk * 8192 + (wn * 64 + rl) * 64 + slotr;  // B region

#define STAGE(t, base)                                                         \
  {                                                                            \
    int kk_ = (t) >> 2, cb_ = (t) & 3;                                         \
    int kh_ = kk_ / 3, kw_ = kk_ - kh_ * 3;                                    \
    int offA_ = kh_ * 16384 + kw_ * 256 + cb_ * 64;                            \
    int offB_ = kk_ * 65536 + cb_ * 64;                                        \
    unsigned short* bA = (unsigned short*)(base);                              \
    unsigned short* bB = (unsigned short*)((char*)(base) + 16384);             \
    gload16(xb + gA0 + offA_,      bA + tid * 8);                              \
    gload16(xb + gA1 + offA_,      bA + (tid + 256) * 8);                      \
    gload16(xb + gA0 + offA_ + 32, bA + (tid + 512) * 8);                      \
    gload16(xb + gA1 + offA_ + 32, bA + (tid + 768) * 8);                      \
    gload16(K2t + offB_ + fB0,      bB + tid * 8);                             \
    gload16(K2t + offB_ + fB1,      bB + (tid + 256) * 8);                     \
    gload16(K2t + offB_ + fB0 + 32, bB + (tid + 512) * 8);                     \
    gload16(K2t + offB_ + fB1 + 32, bB + (tid + 768) * 8);                     \
  }

  STAGE(0, smem);

  for (int t = 0; t < 36; ++t) {
    char* cur = smem + (t & 1) * 32768;
    if (t < 35) STAGE(t + 1, smem + ((t + 1) & 1) * 32768);
    if (t == 35) asm volatile("s_waitcnt vmcnt(0)" ::: "memory");
    else         asm volatile("s_waitcnt vmcnt(8)" ::: "memory");
    __builtin_amdgcn_sched_barrier(0);
    __builtin_amdgcn_s_barrier();
    __builtin_amdgcn_sched_barrier(0);

    bf16x8 bfr[4];
#pragma unroll
    for (int ni = 0; ni < 4; ++ni)
      bfr[ni] = *(const bf16x8*)(cur + boff + ni * 1024);
    bf16x8 a0 = *(const bf16x8*)(cur + aoff);
    bf16x8 a1 = *(const bf16x8*)(cur + aoff + 1024);
#pragma unroll
    for (int j = 0; j < 4; ++j) {
      bf16x8 a2, a3;
      if (j < 3) {
        a2 = *(const bf16x8*)(cur + aoff + (2 * j + 2) * 1024);
        a3 = *(const bf16x8*)(cur + aoff + (2 * j + 3) * 1024);
      }
      __builtin_amdgcn_s_setprio(1);
#pragma unroll
      for (int ni = 0; ni < 4; ++ni)
        acc[2 * j][ni] = __builtin_amdgcn_mfma_f32_16x16x32_bf16(
            a0, bfr[ni], acc[2 * j][ni], 0, 0, 0);
#pragma unroll
      for (int ni = 0; ni < 4; ++ni)
        acc[2 * j + 1][ni] = __builtin_amdgcn_mfma_f32_16x16x32_bf16(
            a1, bfr[ni], acc[2 * j + 1][ni], 0, 0, 0);
      __builtin_amdgcn_s_setprio(0);
      a0 = a2; a1 = a3;
    }

    __builtin_amdgcn_sched_barrier(0);
    __builtin_amdgcn_s_barrier();   // protect cur: STAGE(t+2) overwrites it next
    __builtin_amdgcn_sched_barrier(0);
  }

  // epilogue: sk=1 waves stage acc in LDS (64KB exactly); sk=0 adds + stores.
  // D row = kg*4 + r (+16*mi), col = rl (+16*ni +64*wn).
  float* red = (float*)smem;
  if (sk == 1) {
#pragma unroll
    for (int mi = 0; mi < 8; ++mi)
#pragma unroll
      for (int ni = 0; ni < 4; ++ni)
        *(f32x4*)((char*)red + (((wn * 8 + mi) * 4 + ni) * 64 + lane) * 16) =
            acc[mi][ni];
  }
  __syncthreads();
  if (sk == 0) {
#pragma unroll
    for (int mi = 0; mi < 8; ++mi) {
      int mb = m0 + mi * 16 + kg * 4;
#pragma unroll
      for (int ni = 0; ni < 4; ++ni) {
        f32x4 o = *(f32x4*)((char*)red + (((wn * 8 + mi) * 4 + ni) * 64 + lane) * 16);
        o += acc[mi][ni];
        int f = n0 + wn * 64 + ni * 16 + rl;
#pragma unroll
        for (int r = 0; r < 4; ++r) {
          int m = mb + r;
          if (m < M_TOT) out[m * 256 + f] = o[r];
        }
      }
    }
  }
#undef STAGE
}

extern "C" void kernel_launch(void* const* d_in, const int* in_sizes, int n_in,
                              void* d_out, int out_size, void* d_ws, size_t ws_size,
                              hipStream_t stream) {
  const float* x = (const float*)d_in[0];   // [8,64,64,256]
  const float* P = (const float*)d_in[1];   // [256,256]
  const float* Q = (const float*)d_in[2];   // [256,3,3,16]
  const float* S = (const float*)d_in[3];   // [256,16,256]
  float* out = (float*)d_out;               // [8,62,62,256]

  char* ws = (char*)d_ws;
  unsigned short* xb   = (unsigned short*)ws;                        // 16,777,216 B
  unsigned short* K2t  = (unsigned short*)(ws + 16777216);           //  1,179,648 B
  float*          Keff = (float*)(ws + 16777216 + 1179648);          //  2,359,296 B

  keff_k<<<256, 256, 0, stream>>>(Q, S, Keff);
  fused_k<<<4672, 256, 0, stream>>>(x, P, Keff, xb, K2t);
  conv_gemm<<<488, 256, 0, stream>>>(xb, K2t, out);
}